// Round 15
// baseline (163.278 us; speedup 1.0000x reference)
//
#include <hip/hip_runtime.h>
#include <cstdint>
#include <cstddef>

// Problem constants
#define B_   4
#define L_   1024
#define H_   8
#define DK_  64
#define DV_  192
#define HALF_ 96
#define LOG2E_ 1.44269504088896f

typedef _Float16 half8 __attribute__((ext_vector_type(8)));
typedef _Float16 half4v __attribute__((ext_vector_type(4)));
typedef float f32x4 __attribute__((ext_vector_type(4)));

__device__ __forceinline__ void gll16(const void* g, void* lds) {
    __builtin_amdgcn_global_load_lds(
        (const __attribute__((address_space(1))) unsigned int*)g,
        (__attribute__((address_space(3))) unsigned int*)lds, 16, 0, 0);
}

// ---------------- fused prologue ----------------
// block ranges: [0,2048) x->f16 | [2048,2060) We->f16 | [2060,2124) Wq^T |
// [2124,2188) Wk^T | [2188,2380) Wv^T | [2380,2572) Wo^T | [2572,2582) bias |
// [2582,2966) trig tables | [2966,2972) vWe | [2972,3068) Ctrig (shared swizzled
// [sin_j|cos_j] f16 rows — identical across all bh, stored ONCE)
__global__ void k_prologue(const float* __restrict__ x, _Float16* __restrict__ xh,
                           const float* __restrict__ We, _Float16* __restrict__ Weh,
                           const float* __restrict__ Wq, const float* __restrict__ Wk,
                           const float* __restrict__ Wv, const float* __restrict__ Wo,
                           _Float16* __restrict__ Wqkvt, _Float16* __restrict__ Wot,
                           const float* __restrict__ bq, const float* __restrict__ bk,
                           const float* __restrict__ bv, float* __restrict__ bqkv,
                           float* __restrict__ Tsin, float* __restrict__ Tcos,
                           const float* __restrict__ v, float* __restrict__ vWe,
                           _Float16* __restrict__ Ctrig) {
    __shared__ float tile[64][65];
    const int t = blockIdx.x, tid = threadIdx.x;
    if (t < 2048) {
        int i = t * 256 + tid;
        float4 vv = ((const float4*)x)[i];
        half4v h;
        h[0] = (_Float16)vv.x; h[1] = (_Float16)vv.y; h[2] = (_Float16)vv.z; h[3] = (_Float16)vv.w;
        ((half4v*)xh)[i] = h;
    } else if (t < 2060) {
        int i = (t - 2048) * 256 + tid;
        if (i < 192 * 64 / 4) {
            float4 vv = ((const float4*)We)[i];
            half4v h;
            h[0] = (_Float16)vv.x; h[1] = (_Float16)vv.y; h[2] = (_Float16)vv.z; h[3] = (_Float16)vv.w;
            ((half4v*)Weh)[i] = h;
        }
    } else if (t < 2572) {
        const float* src; _Float16* dst; int K, N, bx, by;
        if (t < 2124)      { int rel = t - 2060; src = Wq; dst = Wqkvt;                       K = 512;  N = 512;  bx = rel & 7;   by = rel >> 3; }
        else if (t < 2188) { int rel = t - 2124; src = Wk; dst = Wqkvt + (size_t)512 * 512;   K = 512;  N = 512;  bx = rel & 7;   by = rel >> 3; }
        else if (t < 2380) { int rel = t - 2188; src = Wv; dst = Wqkvt + (size_t)1024 * 512;  K = 512;  N = 1536; bx = rel % 24;  by = rel / 24; }
        else               { int rel = t - 2380; src = Wo; dst = Wot;                         K = 1536; N = 512;  bx = rel & 7;   by = rel >> 3; }
        int n0 = bx << 6, k0 = by << 6;
#pragma unroll
        for (int q = 0; q < 16; ++q) {
            int e = (q << 8) + tid;
            int r = e >> 6, c = e & 63;
            tile[r][c] = src[(size_t)(k0 + r) * N + n0 + c];
        }
        __syncthreads();
#pragma unroll
        for (int q = 0; q < 16; ++q) {
            int e = (q << 8) + tid;
            int r = e >> 6, c = e & 63;
            dst[(size_t)(n0 + r) * K + k0 + c] = (_Float16)tile[c][r];
        }
    } else if (t < 2582) {
        int i = (t - 2572) * 256 + tid;
        if (i < 2560) {
            float vv;
            if (i < 512) vv = bq[i];
            else if (i < 1024) vv = bk[i - 512];
            else vv = bv[i - 1024];
            bqkv[i] = vv;
        }
    } else if (t < 2966) {
        int idx = (t - 2582) * 256 + tid;
        if (idx < L_ * HALF_) {
            int i = idx / HALF_;
            int f = idx - i * HALF_;
            float w = expf(-(float)f * 0.09594104554141865f);   // ln(10000)/96
            float a = (float)i * w;
            Tsin[idx] = sinf(a);
            Tcos[idx] = cosf(a);
        }
    } else if (t < 2972) {
        int idx = (t - 2966) * 256 + tid;
        if (idx < 8 * 192) {
            int h = idx / 192, f = idx - h * 192;
            float acc = 0.f;
#pragma unroll
            for (int k4 = 0; k4 < 16; ++k4) {
                float4 vv = *(const float4*)(v + (h << 6) + (k4 << 2));
                float4 we = *(const float4*)(We + (size_t)f * 64 + (k4 << 2));
                acc += vv.x * we.x + vv.y * we.y + vv.z * we.z + vv.w * we.w;
            }
            vWe[idx] = acc;
        }
    } else {
        // Ctrig: 1024 j-rows x 24 chunks (16B = 8 f16). Chunk lc: [0,12)=sin f=lc*8,
        // [12,24)=cos f=(lc-12)*8. Stored pre-swizzled so the attn LDS copy lands at
        // chunk cc=lc+8 with cc^=(j&7): pos = (lc>>3)*8 + ((lc&7)^(j&7)).
        int idx = (t - 2972) * 256 + tid;
        if (idx < 1024 * 24) {
            int j = idx / 24, lc = idx - j * 24;
            int f0 = (lc < 12) ? (lc << 3) : ((lc - 12) << 3);
            half8 val;
#pragma unroll
            for (int z = 0; z < 8; ++z) {
                float w = expf(-(float)(f0 + z) * 0.09594104554141865f);
                float a = (float)j * w;
                val[z] = (_Float16)((lc < 12) ? sinf(a) : cosf(a));
            }
            int pos = ((lc >> 3) << 3) + ((lc & 7) ^ (j & 7));
            *(half8*)((char*)Ctrig + (size_t)j * 384 + (pos << 4)) = val;
        }
    }
}

// ---------------- fp16 MFMA GEMM: C[M,TNB*nbx] = A[M,K] @ Bt[N,K]^T + bias ----------------
template<int TNB, bool OUT_F16, bool GMODE>
__global__ __launch_bounds__(256) void k_gemm2(
    const _Float16* __restrict__ A, const _Float16* __restrict__ Bt,
    const float* __restrict__ bias, void* __restrict__ Cout,
    int M, int N, int K, int nbx)
{
    constexpr int BUFSZ = 16384 + TNB * 128;
    __shared__ char sm[2 * BUFSZ];
    const int nwg = gridDim.x;
    const int bid = blockIdx.x;
    const int sw = (bid & 7) * (nwg >> 3) + (bid >> 3);   // XCD-chunked (nwg % 8 == 0)
    const int bx = sw % nbx, by = sw / nbx;
    const int m0 = by << 7, n0 = bx * TNB;
    const int tid = threadIdx.x;
    const int lane = tid & 63, l15 = lane & 15, g = lane >> 4;
    const int w = tid >> 6;
    constexpr int AM = (TNB == 128) ? 4 : 2;
    constexpr int BJ = (TNB >= 64) ? 4 : 2;
    const int wm = (TNB == 128) ? ((w >> 1) << 6) : (w << 5);
    const int wn = (TNB == 128) ? ((w & 1) << 6) : 0;

    f32x4 acc[AM][BJ] = {};

    auto stage = [&](int kt, int bufsel) {
        char* As = sm + bufsel * BUFSZ;
        char* Bs = As + 16384;
#pragma unroll
        for (int i2 = 0; i2 < 4; ++i2) {
            int byte = (i2 << 12) + (tid << 4);
            int row = byte >> 7, bso = byte & 127;
            size_t a_off;
            if constexpr (GMODE) {
                int rg = m0 + row;
                a_off = ((((size_t)(rg >> 13) << 10) + (rg & 1023)) * 2560 + (((rg >> 10) & 7) << 6) + (kt << 6)) * 2;
            } else {
                a_off = ((size_t)(m0 + row) * K + (kt << 6)) * 2;
            }
            gll16((const char*)A + a_off + (bso ^ ((row & 7) << 4)), As + byte);
        }
        const char* Bg = (const char*)Bt + ((size_t)n0 * K + (kt << 6)) * 2;
#pragma unroll
        for (int i2 = 0; i2 < (TNB >> 5); ++i2) {
            int byte = (i2 << 12) + (tid << 4);
            int row = byte >> 7, bso = byte & 127;
            gll16(Bg + (size_t)row * (K * 2) + (bso ^ ((row & 7) << 4)), Bs + byte);
        }
    };

    const int nk = K >> 6;
    stage(0, 0);
    __syncthreads();
    for (int kt = 0; kt < nk; ++kt) {
        const int cur = kt & 1;
        if (kt + 1 < nk) stage(kt + 1, cur ^ 1);
        const char* As = sm + cur * BUFSZ;
        const char* Bs = As + 16384;
#pragma unroll
        for (int kq = 0; kq < 2; ++kq) {
            half8 af[AM], bf[BJ];
#pragma unroll
            for (int a = 0; a < AM; ++a) {
                int row = wm + (a << 4) + l15;
                af[a] = *(const half8*)(As + (row << 7) + ((((kq << 2) | g) ^ (row & 7)) << 4));
            }
#pragma unroll
            for (int bj = 0; bj < BJ; ++bj) {
                int row = wn + (bj << 4) + l15;
                bf[bj] = *(const half8*)(Bs + (row << 7) + ((((kq << 2) | g) ^ (row & 7)) << 4));
            }
#pragma unroll
            for (int a = 0; a < AM; ++a)
#pragma unroll
                for (int bj = 0; bj < BJ; ++bj)
                    acc[a][bj] = __builtin_amdgcn_mfma_f32_16x16x32_f16(af[a], bf[bj], acc[a][bj], 0, 0, 0);
        }
        __syncthreads();
    }
#pragma unroll
    for (int a = 0; a < AM; ++a)
#pragma unroll
        for (int bj = 0; bj < BJ; ++bj)
#pragma unroll
            for (int r = 0; r < 4; ++r) {
                int row = m0 + wm + (a << 4) + (g << 2) + r;
                int col = n0 + wn + (bj << 4) + l15;
                float bb;
                if constexpr (GMODE) bb = bias[(((m0 >> 10) & 7) * N) + col];
                else                 bb = bias ? bias[col] : 0.0f;
                float vv = acc[a][bj][r] + bb;
                if (OUT_F16) ((_Float16*)Cout)[(size_t)row * N + col] = (_Float16)vv;
                else         ((float*)Cout)[(size_t)row * N + col] = vv;
            }
}

// ---------------- fused builder: Qext | Ksmall+bias3 | V pack ----------------
// block ranges: [0,4096) qext | [4096,5120) ksmall+bias3 | [5120,6656) pack_v
// Ksmall: 128B rows (K part only, chunk-swizzled); trig part now shared Ctrig.
__global__ void k_build(const _Float16* __restrict__ QKVh, const _Float16* __restrict__ Gf,
                        const float* __restrict__ Tsin, const float* __restrict__ Tcos,
                        const float* __restrict__ u,
                        _Float16* __restrict__ Qext, _Float16* __restrict__ Ksmall,
                        float* __restrict__ bias3, _Float16* __restrict__ Vd) {
    __shared__ float tile[64][65];
    const int t = blockIdx.x, tid = threadIdx.x;
    if (t < 4096) {
        int r = (t << 3) + (tid >> 5);
        int cc = tid & 31;
        int i = r & 1023, h = (r >> 10) & 7, b = r >> 13;
        half8 val;
        if (cc < 8) {
            half8 q = *(const half8*)(QKVh + ((size_t)(b << 10) + i) * 2560 + (h << 6) + (cc << 3));
#pragma unroll
            for (int z = 0; z < 8; ++z) val[z] = (_Float16)((float)q[z] * LOG2E_);
        } else {
            int f = (cc < 20) ? ((cc - 8) << 3) : ((cc - 20) << 3);
            half8 g0 = *(const half8*)(Gf + (size_t)r * 192 + f);
            half8 g1 = *(const half8*)(Gf + (size_t)r * 192 + 96 + f);
            float4 s0 = *(const float4*)(Tsin + i * 96 + f);
            float4 s1 = *(const float4*)(Tsin + i * 96 + f + 4);
            float4 c0 = *(const float4*)(Tcos + i * 96 + f);
            float4 c1 = *(const float4*)(Tcos + i * 96 + f + 4);
            float sv[8] = {s0.x, s0.y, s0.z, s0.w, s1.x, s1.y, s1.z, s1.w};
            float cv[8] = {c0.x, c0.y, c0.z, c0.w, c1.x, c1.y, c1.z, c1.w};
            if (cc < 20) {
#pragma unroll
                for (int z = 0; z < 8; ++z) val[z] = (_Float16)(((float)g0[z] * cv[z] + (float)g1[z] * sv[z]) * LOG2E_);
            } else {
#pragma unroll
                for (int z = 0; z < 8; ++z) val[z] = (_Float16)(((float)g1[z] * cv[z] - (float)g0[z] * sv[z]) * LOG2E_);
            }
        }
        *(half8*)((char*)Qext + (size_t)r * 512 + ((cc ^ (r & 7)) << 4)) = val;
    } else if (t < 5120) {
        // Ksmall + bias3: 32 rows per block, 8 chunks per row
        int r = ((t - 4096) << 5) + (tid >> 3);
        int cc = tid & 7;
        int i = r & 1023, h = (r >> 10) & 7, b = r >> 13;
        half8 val = *(const half8*)(QKVh + ((size_t)(b << 10) + i) * 2560 + 512 + (h << 6) + (cc << 3));
        float4 u0 = *(const float4*)(u + (h << 6) + (cc << 3));
        float4 u1 = *(const float4*)(u + (h << 6) + (cc << 3) + 4);
        float p = (float)val[0] * u0.x + (float)val[1] * u0.y + (float)val[2] * u0.z + (float)val[3] * u0.w
                + (float)val[4] * u1.x + (float)val[5] * u1.y + (float)val[6] * u1.z + (float)val[7] * u1.w;
        p += __shfl_xor(p, 1); p += __shfl_xor(p, 2); p += __shfl_xor(p, 4);
        if (cc == 0) bias3[r] = p * LOG2E_;
        *(half8*)((char*)Ksmall + (size_t)r * 128 + ((cc ^ (r & 7)) << 4)) = val;
    } else {
        int rel = t - 5120;                 // 1536 = 16 x 3 x 32
        int jx = rel & 15, rest = rel >> 4;
        int dy = rest % 3, bh = rest / 3;
        int j0 = jx << 6, d0 = dy << 6;
        int b = bh >> 3, h = bh & 7;
#pragma unroll
        for (int q = 0; q < 16; ++q) {
            int e = (q << 8) + tid;
            int r = e >> 6, c = e & 63;
            tile[r][c] = (float)QKVh[((size_t)(b << 10) + j0 + r) * 2560 + 1024 + h * 192 + d0 + c];
        }
        __syncthreads();
        char* outb = (char*)Vd + (size_t)bh * 192 * 2048;
#pragma unroll
        for (int q = 0; q < 2; ++q) {
            int e = (q << 8) + tid;
            int dr = e >> 3, jc = e & 7;     // dr = d offset 0..63, jc = 8-j chunk
            int d = d0 + dr;
            half8 v;
#pragma unroll
            for (int z = 0; z < 8; ++z) v[z] = (_Float16)tile[(jc << 3) + z][dr];
            *(half8*)(outb + (size_t)d * 2048 + (j0 << 1) + ((jc ^ (d & 7)) << 4)) = v;
        }
    }
}

// ---------------- fused rel-pos flash attention (R12 structure — converged) ----------------
// 16 waves = 4 waves/SIMD forced. K-tile rows assembled from TWO global streams:
// Ksmall (per-bh, 128B rows) + shared Ctrig (384B rows, one copy for all bh).
// Both pre-swizzled; LDS dest stays linear (rule 21). Swizzle cc^(r&7) never
// crosses the chunk<8 / chunk>=8 boundary, so the streams compose exactly.
__global__ __attribute__((amdgpu_flat_work_group_size(1024, 1024)))
void k_attn(
    const _Float16* __restrict__ Qext, const _Float16* __restrict__ Ksmall,
    const _Float16* __restrict__ Ctrig,
    const _Float16* __restrict__ Vd, const float* __restrict__ bias3,
    _Float16* __restrict__ AOh)
{
    __shared__ char smem[131072];   // K0@0 K1@32K V0@64K V1@88K P@112K+w*1K

    const int bid = blockIdx.x;
    const int sw = ((bid & 7) << 5) + (bid >> 3);   // 32 blocks per XCD chunk
    const int bh = sw >> 3;                         // 4 bh per XCD -> L2-resident K/V
    const int i0 = (sw & 7) << 7;                   // 128 q-rows per block
    const int tid = threadIdx.x;
    const int w = tid >> 6, lane = tid & 63, l15 = lane & 15, g = lane >> 4;
    const int rowg = w & 7, jhalf = w >> 3;
    const int b = bh >> 3, h = bh & 7;

    const char* Ksm = (const char*)Ksmall + ((size_t)bh << 10) * 128;
    const char* Ctg = (const char*)Ctrig;
    const char* Vg = (const char*)Vd + (size_t)bh * 192 * 2048;
    const float* b3g = bias3 + (bh << 10);
    char* Pw = smem + 114688 + (w << 10);

    // Q fragments (swizzled global layout): rows i0 + rowg*16 + l15
    half8 qf[8];
    {
        int row = i0 + (rowg << 4) + l15;
        const char* qp = (const char*)Qext + ((size_t)(bh << 10) + row) * 512;
#pragma unroll
        for (int kq = 0; kq < 8; ++kq)
            qf[kq] = *(const half8*)(qp + ((((kq << 2) + g) ^ (row & 7)) << 4));
    }

    f32x4 oacc[12] = {};
    float m_run[4], l_lane[4];
#pragma unroll
    for (int r = 0; r < 4; ++r) { m_run[r] = -3.0e38f; l_lane[r] = 0.f; }

    auto stage = [&](int jt, int bufsel) {
        char* Kb = smem + bufsel * 32768;
        char* Vb = smem + 65536 + bufsel * 24576;
        // K-tile: 64 rows x 512B; chunk cc<8 from Ksmall, cc>=8 from shared Ctrig
        const int cc = tid & 31;
#pragma unroll
        for (int i2 = 0; i2 < 2; ++i2) {
            int byte = (i2 << 14) + (tid << 4);
            int j = (jt << 6) + (byte >> 9);
            const char* src = (cc < 8)
                ? Ksm + (size_t)j * 128 + (cc << 4)
                : Ctg + (size_t)j * 384 + ((cc - 8) << 4);
            gll16(src, Kb + byte);
        }
        {
            int byte = tid << 4;
            int d = byte >> 7, c = byte & 127;
            gll16(Vg + (size_t)d * 2048 + (jt << 7) + c, Vb + byte);
        }
        if (tid < 512) {
            int byte = 16384 + (tid << 4);
            int d = byte >> 7, c = byte & 127;
            gll16(Vg + (size_t)d * 2048 + (jt << 7) + c, Vb + byte);
        }
    };

    stage(0, 0);
    __syncthreads();

    for (int jt = 0; jt < 16; ++jt) {
        const int cur = jt & 1;
        if (jt + 1 < 16) stage(jt + 1, cur ^ 1);
        const char* Kb = smem + cur * 32768;
        const char* Vb = smem + 65536 + cur * 24576;

        // S = Qext @ Kext^T : 1 row-frag x 2 col-frags (wave's 32-col j-half)
        f32x4 s[2];
#pragma unroll
        for (int jn = 0; jn < 2; ++jn) {
            float b3 = b3g[(jt << 6) + (jhalf << 5) + (jn << 4) + l15];
            s[jn] = (f32x4){b3, b3, b3, b3};
        }
        __builtin_amdgcn_s_setprio(1);
#pragma unroll
        for (int kq = 0; kq < 8; ++kq) {
#pragma unroll
            for (int jn = 0; jn < 2; ++jn) {
                int krow = (((jhalf << 1) + jn) << 4) + l15;
                half8 bf = *(const half8*)(Kb + (krow << 9) + ((((kq << 2) + g) ^ (krow & 7)) << 4));
                s[jn] = __builtin_amdgcn_mfma_f32_16x16x32_f16(qf[kq], bf, s[jn], 0, 0, 0);
            }
        }
        __builtin_amdgcn_s_setprio(0);
        // defer-max online softmax (log2 domain)
        bool pass = true;
#pragma unroll
        for (int jn = 0; jn < 2; ++jn)
#pragma unroll
            for (int r = 0; r < 4; ++r) pass &= (s[jn][r] <= m_run[r] + 8.0f);
        if (!__all(pass)) {
#pragma unroll
            for (int r = 0; r < 4; ++r) {
                float tm = fmaxf(s[0][r], s[1][r]);
                tm = fmaxf(tm, __shfl_xor(tm, 1));
                tm = fmaxf(tm, __shfl_xor(tm, 2));
                tm = fmaxf(tm, __shfl_xor(tm, 4));
                tm = fmaxf(tm, __shfl_xor(tm, 8));
                float mnew = fmaxf(m_run[r], tm);
                float al = exp2f(m_run[r] - mnew);
                l_lane[r] *= al;
                m_run[r] = mnew;
#pragma unroll
                for (int dn = 0; dn < 12; ++dn) oacc[dn][r] *= al;
            }
        }
        // P = exp2(s-m) -> wave-private LDS [16 rows][64B], chunk swz
#pragma unroll
        for (int jn = 0; jn < 2; ++jn)
#pragma unroll
            for (int r = 0; r < 4; ++r) {
                float p = exp2f(s[jn][r] - m_run[r]);
                l_lane[r] += p;
                int row = (g << 2) + r;
                int c = ((jn << 1) + (l15 >> 3)) ^ g;
                *(_Float16*)(Pw + (row << 6) + (c << 4) + ((l15 & 7) << 1)) = (_Float16)p;
            }
        // P A-frag back (same wave): row = l15, 8 j at g*8
        half8 pa;
        {
            int c = g ^ ((l15 >> 2) & 3);
            pa = *(const half8*)(Pw + (l15 << 6) + (c << 4));
        }
        // O += P @ V  (16x16x32, inner = wave's 32 j)
        __builtin_amdgcn_s_setprio(1);
#pragma unroll
        for (int dn = 0; dn < 12; ++dn) {
            int d = (dn << 4) + l15;
            half8 vb = *(const half8*)(Vb + (d << 7) + ((((jhalf << 2) + g) ^ (d & 7)) << 4));
            oacc[dn] = __builtin_amdgcn_mfma_f32_16x16x32_f16(pa, vb, oacc[dn], 0, 0, 0);
        }
        __builtin_amdgcn_s_setprio(0);
        __syncthreads();
    }

    // reduce l across the 16 j-lanes (per row)
    float l_run[4];
#pragma unroll
    for (int r = 0; r < 4; ++r) {
        float l = l_lane[r];
        l += __shfl_xor(l, 1);
        l += __shfl_xor(l, 2);
        l += __shfl_xor(l, 4);
        l += __shfl_xor(l, 8);
        l_run[r] = l;
    }

    // ---- combine the two j-halves ----
    float* Cml = (float*)smem;             // [2 jhalf][128 rows][m,l]  (2KB)
    float* Co  = (float*)(smem + 2048);    // [128][196] f32 partial O (100KB)
#pragma unroll
    for (int r = 0; r < 4; ++r)
        if (l15 == 0) {
            int rowi = (rowg << 4) + (g << 2) + r;
            Cml[(((jhalf << 7) + rowi) << 1) + 0] = m_run[r];
            Cml[(((jhalf << 7) + rowi) << 1) + 1] = l_run[r];
        }
    __syncthreads();
    float fs[4], lt[4];
#pragma unroll
    for (int r = 0; r < 4; ++r) {
        int rowi = (rowg << 4) + (g << 2) + r;
        float mo = Cml[((((1 - jhalf) << 7) + rowi) << 1) + 0];
        float lo = Cml[((((1 - jhalf) << 7) + rowi) << 1) + 1];
        float M = fmaxf(m_run[r], mo);
        float f0 = exp2f(m_run[r] - M);
        float f1 = exp2f(mo - M);
        fs[r] = f0;
        lt[r] = l_run[r] * f0 + lo * f1;
    }
    if (jhalf == 1) {
#pragma unroll
        for (int dn = 0; dn < 12; ++dn)
#pragma unroll
            for (int r = 0; r < 4; ++r) {
                int rowi = (rowg << 4) + (g << 2) + r;
                Co[rowi * 196 + (dn << 4) + l15] = oacc[dn][r] * fs[r];
            }
    }
    __syncthreads();
    if (jhalf == 0) {
#pragma unroll
        for (int r = 0; r < 4; ++r) {
            int rowi = (rowg << 4) + (g << 2) + r;
            float inv = 1.0f / lt[r];
#pragma unroll
            for (int dn = 0; dn < 12; ++dn) {
                float ov = (oacc[dn][r] * fs[r] + Co[rowi * 196 + (dn << 4) + l15]) * inv;
                AOh[((size_t)(b << 10) + i0 + rowi) * 1536 + h * 192 + (dn << 4) + l15] = (_Float16)ov;
            }
        }
    }
}

// ---------------- host launch ----------------
extern "C" void kernel_launch(void* const* d_in, const int* in_sizes, int n_in,
                              void* d_out, int out_size, void* d_ws, size_t ws_size,
                              hipStream_t stream) {
    const float* x  = (const float*)d_in[0];
    const float* Wq = (const float*)d_in[1];
    const float* bq = (const float*)d_in[2];
    const float* Wk = (const float*)d_in[3];
    const float* bk = (const float*)d_in[4];
    const float* Wv = (const float*)d_in[5];
    const float* bv = (const float*)d_in[6];
    const float* Wo = (const float*)d_in[7];
    const float* bo = (const float*)d_in[8];
    const float* We = (const float*)d_in[9];
    const float* u  = (const float*)d_in[10];
    const float* v  = (const float*)d_in[11];
    float* out = (float*)d_out;

    char* ws = (char*)d_ws;
    size_t off = 0;
    auto alloc = [&](size_t bytes) -> void* {
        void* p = ws + off;
        off += (bytes + 255) & ~(size_t)255;
        return p;
    };
    _Float16* xh     = (_Float16*)alloc((size_t)4096 * 512 * 2);
    _Float16* Weh    = (_Float16*)alloc((size_t)192 * 64 * 2);
    _Float16* Wqkvt  = (_Float16*)alloc((size_t)2560 * 512 * 2);
    _Float16* Wot    = (_Float16*)alloc((size_t)512 * 1536 * 2);
    float*    bqkv   = (float*)alloc((size_t)2560 * 4);
    float*    Tsin   = (float*)alloc((size_t)1024 * 96 * 4);
    float*    Tcos   = (float*)alloc((size_t)1024 * 96 * 4);
    float*    vWe    = (float*)alloc((size_t)8 * 192 * 4);
    _Float16* Ctrig  = (_Float16*)alloc((size_t)1024 * 192 * 2);
    _Float16* QKVh   = (_Float16*)alloc((size_t)4096 * 2560 * 2);
    _Float16* Gf16   = (_Float16*)alloc((size_t)32768 * 192 * 2);
    _Float16* Qext   = (_Float16*)alloc((size_t)32768 * 256 * 2);
    _Float16* Ksmall = (_Float16*)alloc((size_t)32768 * 64 * 2);
    float*    bias3  = (float*)alloc((size_t)32768 * 4);
    _Float16* Vd     = (_Float16*)alloc((size_t)32 * 192 * 1024 * 2);
    _Float16* AOh    = (_Float16*)alloc((size_t)4096 * 1536 * 2);
    if (off > ws_size) return;  // insufficient workspace -> clean fail

    // fused prologue: converts + transposes + bias + trig + vWe + Ctrig (1 launch)
    k_prologue<<<3068, 256, 0, stream>>>(x, xh, We, Weh, Wq, Wk, Wv, Wo,
                                         Wqkvt, Wot, bq, bk, bv, bqkv, Tsin, Tcos, v, vWe, Ctrig);

    // fused QKV projection (f16 out): [4096,2560] = xh @ Wqkvt^T + bqkv
    k_gemm2<128, true, false><<<640, 256, 0, stream>>>(xh, Wqkvt, bqkv, QKVh, 4096, 2560, 512, 20);

    // G = Q @ We^T + vWe[h]  (A staged directly from QKVh)
    k_gemm2<64, true, true><<<768, 256, 0, stream>>>(QKVh, Weh, vWe, Gf16, 32768, 192, 64, 3);

    // fused builder: Qext | Ksmall+bias3 | V pack (1 launch)
    k_build<<<6656, 256, 0, stream>>>(QKVh, Gf16, Tsin, Tcos, u, Qext, Ksmall, bias3, Vd);

    // fused attention: 256 blocks x 1024 threads (16 waves = 4 waves/SIMD)
    k_attn<<<256, 1024, 0, stream>>>(Qext, Ksmall, Ctrig, Vd, bias3, AOh);

    // output projection -> d_out (f32): TNB=32 -> 512 blocks @ 40KB LDS
    k_gemm2<32, false, false><<<512, 256, 0, stream>>>(AOh, Wot, bo, out, 4096, 512, 1536, 16);
}

// Round 16
// 147.327 us; speedup vs baseline: 1.1083x; 1.1083x over previous
//
#include <hip/hip_runtime.h>
#include <cstdint>
#include <cstddef>

// Problem constants
#define B_   4
#define L_   1024
#define H_   8
#define DK_  64
#define DV_  192
#define HALF_ 96
#define LOG2E_ 1.44269504088896f

typedef _Float16 half8 __attribute__((ext_vector_type(8)));
typedef _Float16 half4v __attribute__((ext_vector_type(4)));
typedef float f32x4 __attribute__((ext_vector_type(4)));

__device__ __forceinline__ void gll16(const void* g, void* lds) {
    __builtin_amdgcn_global_load_lds(
        (const __attribute__((address_space(1))) unsigned int*)g,
        (__attribute__((address_space(3))) unsigned int*)lds, 16, 0, 0);
}

// ---------------- fused prologue: converts + transposes + bias concat + trig + vWe ----------------
// block ranges: [0,2048) x->f16 | [2048,2060) We->f16 | [2060,2124) Wq^T |
// [2124,2188) Wk^T | [2188,2380) Wv^T | [2380,2572) Wo^T | [2572,2582) bias |
// [2582,2966) trig | [2966,2972) vWe[h][f] = v_h . We_f
__global__ void k_prologue(const float* __restrict__ x, _Float16* __restrict__ xh,
                           const float* __restrict__ We, _Float16* __restrict__ Weh,
                           const float* __restrict__ Wq, const float* __restrict__ Wk,
                           const float* __restrict__ Wv, const float* __restrict__ Wo,
                           _Float16* __restrict__ Wqkvt, _Float16* __restrict__ Wot,
                           const float* __restrict__ bq, const float* __restrict__ bk,
                           const float* __restrict__ bv, float* __restrict__ bqkv,
                           float* __restrict__ Tsin, float* __restrict__ Tcos,
                           const float* __restrict__ v, float* __restrict__ vWe) {
    __shared__ float tile[64][65];
    const int t = blockIdx.x, tid = threadIdx.x;
    if (t < 2048) {
        int i = t * 256 + tid;
        float4 vv = ((const float4*)x)[i];
        half4v h;
        h[0] = (_Float16)vv.x; h[1] = (_Float16)vv.y; h[2] = (_Float16)vv.z; h[3] = (_Float16)vv.w;
        ((half4v*)xh)[i] = h;
    } else if (t < 2060) {
        int i = (t - 2048) * 256 + tid;
        if (i < 192 * 64 / 4) {
            float4 vv = ((const float4*)We)[i];
            half4v h;
            h[0] = (_Float16)vv.x; h[1] = (_Float16)vv.y; h[2] = (_Float16)vv.z; h[3] = (_Float16)vv.w;
            ((half4v*)Weh)[i] = h;
        }
    } else if (t < 2572) {
        const float* src; _Float16* dst; int K, N, bx, by;
        if (t < 2124)      { int rel = t - 2060; src = Wq; dst = Wqkvt;                       K = 512;  N = 512;  bx = rel & 7;   by = rel >> 3; }
        else if (t < 2188) { int rel = t - 2124; src = Wk; dst = Wqkvt + (size_t)512 * 512;   K = 512;  N = 512;  bx = rel & 7;   by = rel >> 3; }
        else if (t < 2380) { int rel = t - 2188; src = Wv; dst = Wqkvt + (size_t)1024 * 512;  K = 512;  N = 1536; bx = rel % 24;  by = rel / 24; }
        else               { int rel = t - 2380; src = Wo; dst = Wot;                         K = 1536; N = 512;  bx = rel & 7;   by = rel >> 3; }
        int n0 = bx << 6, k0 = by << 6;
#pragma unroll
        for (int q = 0; q < 16; ++q) {
            int e = (q << 8) + tid;
            int r = e >> 6, c = e & 63;
            tile[r][c] = src[(size_t)(k0 + r) * N + n0 + c];
        }
        __syncthreads();
#pragma unroll
        for (int q = 0; q < 16; ++q) {
            int e = (q << 8) + tid;
            int r = e >> 6, c = e & 63;
            dst[(size_t)(n0 + r) * K + k0 + c] = (_Float16)tile[c][r];
        }
    } else if (t < 2582) {
        int i = (t - 2572) * 256 + tid;
        if (i < 2560) {
            float vv;
            if (i < 512) vv = bq[i];
            else if (i < 1024) vv = bk[i - 512];
            else vv = bv[i - 1024];
            bqkv[i] = vv;
        }
    } else if (t < 2966) {
        int idx = (t - 2582) * 256 + tid;
        if (idx < L_ * HALF_) {
            int i = idx / HALF_;
            int f = idx - i * HALF_;
            float w = expf(-(float)f * 0.09594104554141865f);   // ln(10000)/96
            float a = (float)i * w;
            Tsin[idx] = sinf(a);
            Tcos[idx] = cosf(a);
        }
    } else {
        int idx = (t - 2966) * 256 + tid;
        if (idx < 8 * 192) {
            int h = idx / 192, f = idx - h * 192;
            float acc = 0.f;
#pragma unroll
            for (int k4 = 0; k4 < 16; ++k4) {
                float4 vv = *(const float4*)(v + (h << 6) + (k4 << 2));
                float4 we = *(const float4*)(We + (size_t)f * 64 + (k4 << 2));
                acc += vv.x * we.x + vv.y * we.y + vv.z * we.z + vv.w * we.w;
            }
            vWe[idx] = acc;
        }
    }
}

// ---------------- fp16 MFMA GEMM: C[M,TNB*nbx] = A[M,K] @ Bt[N,K]^T + bias ----------------
// GMODE: A rows come from QKVh layout (row r=(b*8+h)*1024+i -> QKVh[((b<<10)+i)*2560+(h<<6)]),
// and bias is vWe[h][col] (h constant within each 128-row M-tile).
// TNB=128: 4 waves 64x64 quadrants. TNB=64: 4 waves 32x64. TNB=32: 4 waves 32x32
// (BJ=2) -> 40KB LDS -> up to 4 blocks/CU for occupancy on narrow-N GEMMs.
template<int TNB, bool OUT_F16, bool GMODE>
__global__ __launch_bounds__(256) void k_gemm2(
    const _Float16* __restrict__ A, const _Float16* __restrict__ Bt,
    const float* __restrict__ bias, void* __restrict__ Cout,
    int M, int N, int K, int nbx)
{
    constexpr int BUFSZ = 16384 + TNB * 128;
    __shared__ char sm[2 * BUFSZ];
    const int nwg = gridDim.x;
    const int bid = blockIdx.x;
    const int sw = (bid & 7) * (nwg >> 3) + (bid >> 3);   // XCD-chunked (nwg % 8 == 0)
    const int bx = sw % nbx, by = sw / nbx;
    const int m0 = by << 7, n0 = bx * TNB;
    const int tid = threadIdx.x;
    const int lane = tid & 63, l15 = lane & 15, g = lane >> 4;
    const int w = tid >> 6;
    constexpr int AM = (TNB == 128) ? 4 : 2;
    constexpr int BJ = (TNB >= 64) ? 4 : 2;
    const int wm = (TNB == 128) ? ((w >> 1) << 6) : (w << 5);
    const int wn = (TNB == 128) ? ((w & 1) << 6) : 0;

    f32x4 acc[AM][BJ] = {};

    auto stage = [&](int kt, int bufsel) {
        char* As = sm + bufsel * BUFSZ;
        char* Bs = As + 16384;
#pragma unroll
        for (int i2 = 0; i2 < 4; ++i2) {
            int byte = (i2 << 12) + (tid << 4);
            int row = byte >> 7, bso = byte & 127;
            size_t a_off;
            if constexpr (GMODE) {
                int rg = m0 + row;
                a_off = ((((size_t)(rg >> 13) << 10) + (rg & 1023)) * 2560 + (((rg >> 10) & 7) << 6) + (kt << 6)) * 2;
            } else {
                a_off = ((size_t)(m0 + row) * K + (kt << 6)) * 2;
            }
            gll16((const char*)A + a_off + (bso ^ ((row & 7) << 4)), As + byte);
        }
        const char* Bg = (const char*)Bt + ((size_t)n0 * K + (kt << 6)) * 2;
#pragma unroll
        for (int i2 = 0; i2 < (TNB >> 5); ++i2) {
            int byte = (i2 << 12) + (tid << 4);
            int row = byte >> 7, bso = byte & 127;
            gll16(Bg + (size_t)row * (K * 2) + (bso ^ ((row & 7) << 4)), Bs + byte);
        }
    };

    const int nk = K >> 6;
    stage(0, 0);
    __syncthreads();
    for (int kt = 0; kt < nk; ++kt) {
        const int cur = kt & 1;
        if (kt + 1 < nk) stage(kt + 1, cur ^ 1);
        const char* As = sm + cur * BUFSZ;
        const char* Bs = As + 16384;
#pragma unroll
        for (int kq = 0; kq < 2; ++kq) {
            half8 af[AM], bf[BJ];
#pragma unroll
            for (int a = 0; a < AM; ++a) {
                int row = wm + (a << 4) + l15;
                af[a] = *(const half8*)(As + (row << 7) + ((((kq << 2) | g) ^ (row & 7)) << 4));
            }
#pragma unroll
            for (int bj = 0; bj < BJ; ++bj) {
                int row = wn + (bj << 4) + l15;
                bf[bj] = *(const half8*)(Bs + (row << 7) + ((((kq << 2) | g) ^ (row & 7)) << 4));
            }
#pragma unroll
            for (int a = 0; a < AM; ++a)
#pragma unroll
                for (int bj = 0; bj < BJ; ++bj)
                    acc[a][bj] = __builtin_amdgcn_mfma_f32_16x16x32_f16(af[a], bf[bj], acc[a][bj], 0, 0, 0);
        }
        __syncthreads();
    }
#pragma unroll
    for (int a = 0; a < AM; ++a)
#pragma unroll
        for (int bj = 0; bj < BJ; ++bj)
#pragma unroll
            for (int r = 0; r < 4; ++r) {
                int row = m0 + wm + (a << 4) + (g << 2) + r;
                int col = n0 + wn + (bj << 4) + l15;
                float bb;
                if constexpr (GMODE) bb = bias[(((m0 >> 10) & 7) * N) + col];
                else                 bb = bias ? bias[col] : 0.0f;
                float vv = acc[a][bj][r] + bb;
                if (OUT_F16) ((_Float16*)Cout)[(size_t)row * N + col] = (_Float16)vv;
                else         ((float*)Cout)[(size_t)row * N + col] = vv;
            }
}

// ---------------- fused builder: Qext | Kext+bias3 | V pack (KVBLK=64 layout) ----------------
// block ranges: [0,4096) qext | [4096,8192) kext | [8192,9728) pack_v
__global__ void k_build(const _Float16* __restrict__ QKVh, const _Float16* __restrict__ Gf,
                        const float* __restrict__ Tsin, const float* __restrict__ Tcos,
                        const float* __restrict__ u,
                        _Float16* __restrict__ Qext, _Float16* __restrict__ Kext,
                        float* __restrict__ bias3, _Float16* __restrict__ Vd) {
    __shared__ float tile[64][65];
    const int t = blockIdx.x, tid = threadIdx.x;
    if (t < 8192) {
        const bool isQ = (t < 4096);
        int r = ((isQ ? t : t - 4096) << 3) + (tid >> 5);
        int cc = tid & 31;
        int i = r & 1023, h = (r >> 10) & 7, b = r >> 13;
        half8 val;
        if (cc < 8) {
            if (isQ) {
                half8 q = *(const half8*)(QKVh + ((size_t)(b << 10) + i) * 2560 + (h << 6) + (cc << 3));
#pragma unroll
                for (int z = 0; z < 8; ++z) val[z] = (_Float16)((float)q[z] * LOG2E_);
            } else {
                val = *(const half8*)(QKVh + ((size_t)(b << 10) + i) * 2560 + 512 + (h << 6) + (cc << 3));
                float4 u0 = *(const float4*)(u + (h << 6) + (cc << 3));
                float4 u1 = *(const float4*)(u + (h << 6) + (cc << 3) + 4);
                float p = (float)val[0] * u0.x + (float)val[1] * u0.y + (float)val[2] * u0.z + (float)val[3] * u0.w
                        + (float)val[4] * u1.x + (float)val[5] * u1.y + (float)val[6] * u1.z + (float)val[7] * u1.w;
                p += __shfl_xor(p, 1); p += __shfl_xor(p, 2); p += __shfl_xor(p, 4);
                if (cc == 0) bias3[r] = p * LOG2E_;
            }
        } else {
            int f = (cc < 20) ? ((cc - 8) << 3) : ((cc - 20) << 3);
            if (isQ) {
                half8 g0 = *(const half8*)(Gf + (size_t)r * 192 + f);
                half8 g1 = *(const half8*)(Gf + (size_t)r * 192 + 96 + f);
                float4 s0 = *(const float4*)(Tsin + i * 96 + f);
                float4 s1 = *(const float4*)(Tsin + i * 96 + f + 4);
                float4 c0 = *(const float4*)(Tcos + i * 96 + f);
                float4 c1 = *(const float4*)(Tcos + i * 96 + f + 4);
                float sv[8] = {s0.x, s0.y, s0.z, s0.w, s1.x, s1.y, s1.z, s1.w};
                float cv[8] = {c0.x, c0.y, c0.z, c0.w, c1.x, c1.y, c1.z, c1.w};
                if (cc < 20) {
#pragma unroll
                    for (int z = 0; z < 8; ++z) val[z] = (_Float16)(((float)g0[z] * cv[z] + (float)g1[z] * sv[z]) * LOG2E_);
                } else {
#pragma unroll
                    for (int z = 0; z < 8; ++z) val[z] = (_Float16)(((float)g1[z] * cv[z] - (float)g0[z] * sv[z]) * LOG2E_);
                }
            } else {
                const float* T = (cc < 20) ? Tsin : Tcos;
                float4 t0 = *(const float4*)(T + i * 96 + f);
                float4 t1 = *(const float4*)(T + i * 96 + f + 4);
                float tv[8] = {t0.x, t0.y, t0.z, t0.w, t1.x, t1.y, t1.z, t1.w};
#pragma unroll
                for (int z = 0; z < 8; ++z) val[z] = (_Float16)tv[z];
            }
        }
        _Float16* dst = isQ ? Qext : Kext;
        *(half8*)((char*)dst + (size_t)r * 512 + ((cc ^ (r & 7)) << 4)) = val;
    } else {
        int rel = t - 8192;                 // 1536 = 16 x 3 x 32
        int jx = rel & 15, rest = rel >> 4;
        int dy = rest % 3, bh = rest / 3;
        int j0 = jx << 6, d0 = dy << 6;
        int b = bh >> 3, h = bh & 7;
#pragma unroll
        for (int q = 0; q < 16; ++q) {
            int e = (q << 8) + tid;
            int r = e >> 6, c = e & 63;
            tile[r][c] = (float)QKVh[((size_t)(b << 10) + j0 + r) * 2560 + 1024 + h * 192 + d0 + c];
        }
        __syncthreads();
        char* outb = (char*)Vd + (size_t)bh * 192 * 2048;
#pragma unroll
        for (int q = 0; q < 2; ++q) {
            int e = (q << 8) + tid;
            int dr = e >> 3, jc = e & 7;     // dr = d offset 0..63, jc = 8-j chunk
            int d = d0 + dr;
            half8 v;
#pragma unroll
            for (int z = 0; z < 8; ++z) v[z] = (_Float16)tile[(jc << 3) + z][dr];
            *(half8*)(outb + (size_t)d * 2048 + (j0 << 1) + ((jc ^ (d & 7)) << 4)) = v;
        }
    }
}

// ---------------- fused rel-pos flash attention (R12/R14 structure — converged) ----------------
// 16 waves = 4 waves/SIMD forced co-residency; 64-VGPR cap at 1024 threads is a
// toolchain invariant, and the wave's minimal state (~88) > 64, so ~24-reg spill
// is structural but still the best measured cell (79.5us vs 86.5 no-spill).
// R15's split-source K staging (Ksmall+Ctrig) falsified: divergent per-lane src
// raised spill (WRITE 31.5->42MB, attn 79.5->99us). Single-stream staging is
// the register-minimal form.
__global__ __attribute__((amdgpu_flat_work_group_size(1024, 1024)))
void k_attn(
    const _Float16* __restrict__ Qext, const _Float16* __restrict__ Kext,
    const _Float16* __restrict__ Vd, const float* __restrict__ bias3,
    _Float16* __restrict__ AOh)
{
    __shared__ char smem[131072];   // K0@0 K1@32K V0@64K V1@88K P@112K+w*1K

    const int bid = blockIdx.x;
    const int sw = ((bid & 7) << 5) + (bid >> 3);   // 32 blocks per XCD chunk
    const int bh = sw >> 3;                         // 4 bh per XCD -> L2-resident K/V
    const int i0 = (sw & 7) << 7;                   // 128 q-rows per block
    const int tid = threadIdx.x;
    const int w = tid >> 6, lane = tid & 63, l15 = lane & 15, g = lane >> 4;
    const int rowg = w & 7, jhalf = w >> 3;
    const int b = bh >> 3, h = bh & 7;

    const char* Kg = (const char*)Kext + ((size_t)bh << 10) * 512;
    const char* Vg = (const char*)Vd + (size_t)bh * 192 * 2048;
    const float* b3g = bias3 + (bh << 10);
    char* Pw = smem + 114688 + (w << 10);

    // Q fragments (swizzled global layout): rows i0 + rowg*16 + l15
    half8 qf[8];
    {
        int row = i0 + (rowg << 4) + l15;
        const char* qp = (const char*)Qext + ((size_t)(bh << 10) + row) * 512;
#pragma unroll
        for (int kq = 0; kq < 8; ++kq)
            qf[kq] = *(const half8*)(qp + ((((kq << 2) + g) ^ (row & 7)) << 4));
    }

    f32x4 oacc[12] = {};
    float m_run[4], l_lane[4];
#pragma unroll
    for (int r = 0; r < 4; ++r) { m_run[r] = -3.0e38f; l_lane[r] = 0.f; }

    auto stage = [&](int jt, int bufsel) {
        char* Kb = smem + bufsel * 32768;
        char* Vb = smem + 65536 + bufsel * 24576;
        const char* Ksrc = Kg + (size_t)jt * 32768;
#pragma unroll
        for (int i2 = 0; i2 < 2; ++i2) {
            int byte = (i2 << 14) + (tid << 4);
            gll16(Ksrc + byte, Kb + byte);
        }
        {
            int byte = tid << 4;
            int d = byte >> 7, c = byte & 127;
            gll16(Vg + (size_t)d * 2048 + (jt << 7) + c, Vb + byte);
        }
        if (tid < 512) {
            int byte = 16384 + (tid << 4);
            int d = byte >> 7, c = byte & 127;
            gll16(Vg + (size_t)d * 2048 + (jt << 7) + c, Vb + byte);
        }
    };

    stage(0, 0);
    __syncthreads();

    for (int jt = 0; jt < 16; ++jt) {
        const int cur = jt & 1;
        if (jt + 1 < 16) stage(jt + 1, cur ^ 1);
        const char* Kb = smem + cur * 32768;
        const char* Vb = smem + 65536 + cur * 24576;

        // S = Qext @ Kext^T : 1 row-frag x 2 col-frags (wave's 32-col j-half)
        f32x4 s[2];
#pragma unroll
        for (int jn = 0; jn < 2; ++jn) {
            float b3 = b3g[(jt << 6) + (jhalf << 5) + (jn << 4) + l15];
            s[jn] = (f32x4){b3, b3, b3, b3};
        }
        __builtin_amdgcn_s_setprio(1);
#pragma unroll
        for (int kq = 0; kq < 8; ++kq) {
#pragma unroll
            for (int jn = 0; jn < 2; ++jn) {
                int krow = (((jhalf << 1) + jn) << 4) + l15;
                half8 bf = *(const half8*)(Kb + (krow << 9) + ((((kq << 2) + g) ^ (krow & 7)) << 4));
                s[jn] = __builtin_amdgcn_mfma_f32_16x16x32_f16(qf[kq], bf, s[jn], 0, 0, 0);
            }
        }
        __builtin_amdgcn_s_setprio(0);
        // defer-max online softmax (log2 domain)
        bool pass = true;
#pragma unroll
        for (int jn = 0; jn < 2; ++jn)
#pragma unroll
            for (int r = 0; r < 4; ++r) pass &= (s[jn][r] <= m_run[r] + 8.0f);
        if (!__all(pass)) {
#pragma unroll
            for (int r = 0; r < 4; ++r) {
                float tm = fmaxf(s[0][r], s[1][r]);
                tm = fmaxf(tm, __shfl_xor(tm, 1));
                tm = fmaxf(tm, __shfl_xor(tm, 2));
                tm = fmaxf(tm, __shfl_xor(tm, 4));
                tm = fmaxf(tm, __shfl_xor(tm, 8));
                float mnew = fmaxf(m_run[r], tm);
                float al = exp2f(m_run[r] - mnew);
                l_lane[r] *= al;
                m_run[r] = mnew;
#pragma unroll
                for (int dn = 0; dn < 12; ++dn) oacc[dn][r] *= al;
            }
        }
        // P = exp2(s-m) -> wave-private LDS [16 rows][64B], chunk swz
#pragma unroll
        for (int jn = 0; jn < 2; ++jn)
#pragma unroll
            for (int r = 0; r < 4; ++r) {
                float p = exp2f(s[jn][r] - m_run[r]);
                l_lane[r] += p;
                int row = (g << 2) + r;
                int c = ((jn << 1) + (l15 >> 3)) ^ g;
                *(_Float16*)(Pw + (row << 6) + (c << 4) + ((l15 & 7) << 1)) = (_Float16)p;
            }
        // P A-frag back (same wave): row = l15, 8 j at g*8
        half8 pa;
        {
            int c = g ^ ((l15 >> 2) & 3);
            pa = *(const half8*)(Pw + (l15 << 6) + (c << 4));
        }
        // O += P @ V  (16x16x32, inner = wave's 32 j)
        __builtin_amdgcn_s_setprio(1);
#pragma unroll
        for (int dn = 0; dn < 12; ++dn) {
            int d = (dn << 4) + l15;
            half8 vb = *(const half8*)(Vb + (d << 7) + ((((jhalf << 2) + g) ^ (d & 7)) << 4));
            oacc[dn] = __builtin_amdgcn_mfma_f32_16x16x32_f16(pa, vb, oacc[dn], 0, 0, 0);
        }
        __builtin_amdgcn_s_setprio(0);
        __syncthreads();
    }

    // reduce l across the 16 j-lanes (per row)
    float l_run[4];
#pragma unroll
    for (int r = 0; r < 4; ++r) {
        float l = l_lane[r];
        l += __shfl_xor(l, 1);
        l += __shfl_xor(l, 2);
        l += __shfl_xor(l, 4);
        l += __shfl_xor(l, 8);
        l_run[r] = l;
    }

    // ---- combine the two j-halves ----
    float* Cml = (float*)smem;             // [2 jhalf][128 rows][m,l]  (2KB)
    float* Co  = (float*)(smem + 2048);    // [128][196] f32 partial O (100KB)
#pragma unroll
    for (int r = 0; r < 4; ++r)
        if (l15 == 0) {
            int rowi = (rowg << 4) + (g << 2) + r;
            Cml[(((jhalf << 7) + rowi) << 1) + 0] = m_run[r];
            Cml[(((jhalf << 7) + rowi) << 1) + 1] = l_run[r];
        }
    __syncthreads();
    float fs[4], lt[4];
#pragma unroll
    for (int r = 0; r < 4; ++r) {
        int rowi = (rowg << 4) + (g << 2) + r;
        float mo = Cml[((((1 - jhalf) << 7) + rowi) << 1) + 0];
        float lo = Cml[((((1 - jhalf) << 7) + rowi) << 1) + 1];
        float M = fmaxf(m_run[r], mo);
        float f0 = exp2f(m_run[r] - M);
        float f1 = exp2f(mo - M);
        fs[r] = f0;
        lt[r] = l_run[r] * f0 + lo * f1;
    }
    if (jhalf == 1) {
#pragma unroll
        for (int dn = 0; dn < 12; ++dn)
#pragma unroll
            for (int r = 0; r < 4; ++r) {
                int rowi = (rowg << 4) + (g << 2) + r;
                Co[rowi * 196 + (dn << 4) + l15] = oacc[dn][r] * fs[r];
            }
    }
    __syncthreads();
    if (jhalf == 0) {
#pragma unroll
        for (int r = 0; r < 4; ++r) {
            int rowi = (rowg << 4) + (g << 2) + r;
            float inv = 1.0f / lt[r];
#pragma unroll
            for (int dn = 0; dn < 12; ++dn) {
                float ov = (oacc[dn][r] * fs[r] + Co[rowi * 196 + (dn << 4) + l15]) * inv;
                AOh[((size_t)(b << 10) + i0 + rowi) * 1536 + h * 192 + (dn << 4) + l15] = (_Float16)ov;
            }
        }
    }
}

// ---------------- host launch ----------------
extern "C" void kernel_launch(void* const* d_in, const int* in_sizes, int n_in,
                              void* d_out, int out_size, void* d_ws, size_t ws_size,
                              hipStream_t stream) {
    const float* x  = (const float*)d_in[0];
    const float* Wq = (const float*)d_in[1];
    const float* bq = (const float*)d_in[2];
    const float* Wk = (const float*)d_in[3];
    const float* bk = (const float*)d_in[4];
    const float* Wv = (const float*)d_in[5];
    const float* bv = (const float*)d_in[6];
    const float* Wo = (const float*)d_in[7];
    const float* bo = (const float*)d_in[8];
    const float* We = (const float*)d_in[9];
    const float* u  = (const float*)d_in[10];
    const float* v  = (const float*)d_in[11];
    float* out = (float*)d_out;

    char* ws = (char*)d_ws;
    size_t off = 0;
    auto alloc = [&](size_t bytes) -> void* {
        void* p = ws + off;
        off += (bytes + 255) & ~(size_t)255;
        return p;
    };
    _Float16* xh    = (_Float16*)alloc((size_t)4096 * 512 * 2);
    _Float16* Weh   = (_Float16*)alloc((size_t)192 * 64 * 2);
    _Float16* Wqkvt = (_Float16*)alloc((size_t)2560 * 512 * 2);
    _Float16* Wot   = (_Float16*)alloc((size_t)512 * 1536 * 2);
    float*    bqkv  = (float*)alloc((size_t)2560 * 4);
    float*    Tsin  = (float*)alloc((size_t)1024 * 96 * 4);
    float*    Tcos  = (float*)alloc((size_t)1024 * 96 * 4);
    float*    vWe   = (float*)alloc((size_t)8 * 192 * 4);
    _Float16* QKVh  = (_Float16*)alloc((size_t)4096 * 2560 * 2);
    _Float16* Gf16  = (_Float16*)alloc((size_t)32768 * 192 * 2);
    _Float16* Qext  = (_Float16*)alloc((size_t)32768 * 256 * 2);
    _Float16* Kext  = (_Float16*)alloc((size_t)32768 * 256 * 2);
    float*    bias3 = (float*)alloc((size_t)32768 * 4);
    _Float16* Vd    = (_Float16*)alloc((size_t)32 * 192 * 1024 * 2);
    _Float16* AOh   = (_Float16*)alloc((size_t)4096 * 1536 * 2);
    if (off > ws_size) return;  // insufficient workspace -> clean fail

    // fused prologue: converts + transposes + bias + trig + vWe (1 launch)
    k_prologue<<<2972, 256, 0, stream>>>(x, xh, We, Weh, Wq, Wk, Wv, Wo,
                                         Wqkvt, Wot, bq, bk, bv, bqkv, Tsin, Tcos, v, vWe);

    // fused QKV projection (f16 out): [4096,2560] = xh @ Wqkvt^T + bqkv
    k_gemm2<128, true, false><<<640, 256, 0, stream>>>(xh, Wqkvt, bqkv, QKVh, 4096, 2560, 512, 20);

    // G = Q @ We^T + vWe[h]  (A staged directly from QKVh)
    k_gemm2<64, true, true><<<768, 256, 0, stream>>>(QKVh, Weh, vWe, Gf16, 32768, 192, 64, 3);

    // fused builder: Qext | Kext+bias3 | V pack (1 launch)
    k_build<<<9728, 256, 0, stream>>>(QKVh, Gf16, Tsin, Tcos, u, Qext, Kext, bias3, Vd);

    // fused attention: 256 blocks x 1024 threads (16 waves = 4 waves/SIMD)
    k_attn<<<256, 1024, 0, stream>>>(Qext, Kext, Vd, bias3, AOh);

    // output projection -> d_out (f32): TNB=32 -> 512 blocks @ 40KB LDS
    k_gemm2<32, false, false><<<512, 256, 0, stream>>>(AOh, Wot, bo, out, 4096, 512, 1536, 16);
}